// Round 2
// baseline (2372.009 us; speedup 1.0000x reference)
//
#include <hip/hip_runtime.h>

#define BSZ 4
#define DD 1024
#define NHH 16
#define DHH 64
#define HHH 1024
#define LLL 1024

// C[r][n] = sum_k A[r][k]*B[n][k] + bias[n]; fp32.
// BM=BN=64, BK=16; 256 threads, 4x4 microtile; tiles staged k-major in LDS.
__global__ __launch_bounds__(256, 2) void gemm_nt_bias(
    const float* __restrict__ A, const float* __restrict__ B,
    const float* __restrict__ bias, float* __restrict__ C,
    int M, int N, int K)
{
    __shared__ float As[16][64];
    __shared__ float Bs[16][64];
    const int t  = threadIdx.x;
    const int r0 = blockIdx.x << 6;
    const int n0 = blockIdx.y << 6;
    const int tx = t & 15;
    const int ty = t >> 4;
    const int lrow = t >> 2;          // 0..63
    const int lk   = (t & 3) << 2;    // 0,4,8,12
    float acc[4][4] = {};

    const float* Ap = A + (size_t)(r0 + lrow) * K + lk;
    const float* Bp = B + (size_t)(n0 + lrow) * K + lk;

    for (int k0 = 0; k0 < K; k0 += 16) {
        const float4 av = *(const float4*)(Ap + k0);
        const float4 bv = *(const float4*)(Bp + k0);
        __syncthreads();
        As[lk + 0][lrow] = av.x;
        As[lk + 1][lrow] = av.y;
        As[lk + 2][lrow] = av.z;
        As[lk + 3][lrow] = av.w;
        Bs[lk + 0][lrow] = bv.x;
        Bs[lk + 1][lrow] = bv.y;
        Bs[lk + 2][lrow] = bv.z;
        Bs[lk + 3][lrow] = bv.w;
        __syncthreads();
        #pragma unroll
        for (int kk = 0; kk < 16; kk++) {
            const float4 a = *(const float4*)&As[kk][ty << 2];
            const float4 b = *(const float4*)&Bs[kk][tx << 2];
            acc[0][0] = fmaf(a.x, b.x, acc[0][0]);
            acc[0][1] = fmaf(a.x, b.y, acc[0][1]);
            acc[0][2] = fmaf(a.x, b.z, acc[0][2]);
            acc[0][3] = fmaf(a.x, b.w, acc[0][3]);
            acc[1][0] = fmaf(a.y, b.x, acc[1][0]);
            acc[1][1] = fmaf(a.y, b.y, acc[1][1]);
            acc[1][2] = fmaf(a.y, b.z, acc[1][2]);
            acc[1][3] = fmaf(a.y, b.w, acc[1][3]);
            acc[2][0] = fmaf(a.z, b.x, acc[2][0]);
            acc[2][1] = fmaf(a.z, b.y, acc[2][1]);
            acc[2][2] = fmaf(a.z, b.z, acc[2][2]);
            acc[2][3] = fmaf(a.z, b.w, acc[2][3]);
            acc[3][0] = fmaf(a.w, b.x, acc[3][0]);
            acc[3][1] = fmaf(a.w, b.y, acc[3][1]);
            acc[3][2] = fmaf(a.w, b.z, acc[3][2]);
            acc[3][3] = fmaf(a.w, b.w, acc[3][3]);
        }
    }
    float bb[4];
    #pragma unroll
    for (int j = 0; j < 4; j++) bb[j] = bias[n0 + (tx << 2) + j];
    #pragma unroll
    for (int i = 0; i < 4; i++) {
        float4 ov;
        ov.x = acc[i][0] + bb[0];
        ov.y = acc[i][1] + bb[1];
        ov.z = acc[i][2] + bb[2];
        ov.w = acc[i][3] + bb[3];
        *(float4*)(C + (size_t)(r0 + (ty << 2) + i) * N + n0 + (tx << 2)) = ov;
    }
}

// Fused per-(p, l-tile) kernel: hid = relu(q@w1+b1) -> logits = hid@w2+b2+mask
// -> softmax -> P@V. Block = 256 threads, 16 rows of l; thread t owns m=4t..4t+3.
// p decodes two ways (reference's scramble): logits side (kq=p/BS, bq=p%BS),
// v/output side (bv=p/NH, kv=p%NH).
__global__ __launch_bounds__(256, 2) void attn_fused(
    const float* __restrict__ proj,   // (L*BS, 2D): [:,0:1024]=q, [:,1024:2048]=v
    const float* __restrict__ w1,     // (NH, DH, H)
    const float* __restrict__ b1,     // (NH, H)
    const float* __restrict__ w2,     // (NH, H, L)
    const float* __restrict__ b2,     // (NH, L)
    const float* __restrict__ mask,   // (L, L)
    float* __restrict__ attn_out)     // (L*BS, D)
{
    __shared__ float hid_s[16 * HHH];   // hid, then reused for probs
    __shared__ float qs[16][64];
    __shared__ float wredm[4][16];
    __shared__ float wreds[4][16];

    const int t    = threadIdx.x;
    const int l0   = blockIdx.x << 4;
    const int p    = blockIdx.y;
    const int kq   = p >> 2;            // p / BS
    const int bq   = p & 3;             // p % BS
    const int bv   = p >> 4;            // p / NH
    const int kv   = p & 15;            // p % NH
    const int lane = t & 63;
    const int wave = t >> 6;

    // stage q: 16 rows x 64
    #pragma unroll
    for (int e = 0; e < 4; e++) {
        const int idx = t + (e << 8);
        const int r = idx >> 6, c = idx & 63;
        qs[r][c] = proj[(size_t)((l0 + r) * BSZ + bq) * (2 * DD) + kq * DHH + c];
    }
    __syncthreads();

    float acc[16][4];
    #pragma unroll
    for (int r = 0; r < 16; r++) {
        #pragma unroll
        for (int j = 0; j < 4; j++) acc[r][j] = 0.f;
    }

    // ---- hid = relu(q @ w1 + b1): this thread computes h = 4t..4t+3, all 16 rows
    {
        const float4* w1p = (const float4*)(w1 + (size_t)kq * DHH * HHH) + t;
        for (int c = 0; c < 64; c += 4) {
            const float4 u0 = w1p[(c + 0) << 8];
            const float4 u1 = w1p[(c + 1) << 8];
            const float4 u2 = w1p[(c + 2) << 8];
            const float4 u3 = w1p[(c + 3) << 8];
            #pragma unroll
            for (int r = 0; r < 16; r++) {
                const float4 qv = *(const float4*)&qs[r][c];
                acc[r][0] = fmaf(qv.x, u0.x, acc[r][0]);
                acc[r][1] = fmaf(qv.x, u0.y, acc[r][1]);
                acc[r][2] = fmaf(qv.x, u0.z, acc[r][2]);
                acc[r][3] = fmaf(qv.x, u0.w, acc[r][3]);
                acc[r][0] = fmaf(qv.y, u1.x, acc[r][0]);
                acc[r][1] = fmaf(qv.y, u1.y, acc[r][1]);
                acc[r][2] = fmaf(qv.y, u1.z, acc[r][2]);
                acc[r][3] = fmaf(qv.y, u1.w, acc[r][3]);
                acc[r][0] = fmaf(qv.z, u2.x, acc[r][0]);
                acc[r][1] = fmaf(qv.z, u2.y, acc[r][1]);
                acc[r][2] = fmaf(qv.z, u2.z, acc[r][2]);
                acc[r][3] = fmaf(qv.z, u2.w, acc[r][3]);
                acc[r][0] = fmaf(qv.w, u3.x, acc[r][0]);
                acc[r][1] = fmaf(qv.w, u3.y, acc[r][1]);
                acc[r][2] = fmaf(qv.w, u3.z, acc[r][2]);
                acc[r][3] = fmaf(qv.w, u3.w, acc[r][3]);
            }
        }
        const float4 b1v = *((const float4*)(b1 + (size_t)kq * HHH) + t);
        #pragma unroll
        for (int r = 0; r < 16; r++) {
            float4 hv;
            hv.x = fmaxf(acc[r][0] + b1v.x, 0.f);
            hv.y = fmaxf(acc[r][1] + b1v.y, 0.f);
            hv.z = fmaxf(acc[r][2] + b1v.z, 0.f);
            hv.w = fmaxf(acc[r][3] + b1v.w, 0.f);
            *(float4*)&hid_s[r * HHH + (t << 2)] = hv;
        }
    }
    __syncthreads();

    // ---- logits = hid @ w2 (K=1024), acc[16][4] in registers
    #pragma unroll
    for (int r = 0; r < 16; r++) {
        #pragma unroll
        for (int j = 0; j < 4; j++) acc[r][j] = 0.f;
    }
    {
        const float4* w2p = (const float4*)(w2 + (size_t)kq * HHH * LLL) + t;
        for (int h = 0; h < HHH; h += 4) {
            const float4 u0 = w2p[(h + 0) << 8];
            const float4 u1 = w2p[(h + 1) << 8];
            const float4 u2 = w2p[(h + 2) << 8];
            const float4 u3 = w2p[(h + 3) << 8];
            #pragma unroll
            for (int r = 0; r < 16; r++) {
                const float4 hv = *(const float4*)&hid_s[r * HHH + h];
                acc[r][0] = fmaf(hv.x, u0.x, acc[r][0]);
                acc[r][1] = fmaf(hv.x, u0.y, acc[r][1]);
                acc[r][2] = fmaf(hv.x, u0.z, acc[r][2]);
                acc[r][3] = fmaf(hv.x, u0.w, acc[r][3]);
                acc[r][0] = fmaf(hv.y, u1.x, acc[r][0]);
                acc[r][1] = fmaf(hv.y, u1.y, acc[r][1]);
                acc[r][2] = fmaf(hv.y, u1.z, acc[r][2]);
                acc[r][3] = fmaf(hv.y, u1.w, acc[r][3]);
                acc[r][0] = fmaf(hv.z, u2.x, acc[r][0]);
                acc[r][1] = fmaf(hv.z, u2.y, acc[r][1]);
                acc[r][2] = fmaf(hv.z, u2.z, acc[r][2]);
                acc[r][3] = fmaf(hv.z, u2.w, acc[r][3]);
                acc[r][0] = fmaf(hv.w, u3.x, acc[r][0]);
                acc[r][1] = fmaf(hv.w, u3.y, acc[r][1]);
                acc[r][2] = fmaf(hv.w, u3.z, acc[r][2]);
                acc[r][3] = fmaf(hv.w, u3.w, acc[r][3]);
            }
        }
    }
    // bias + additive mask
    {
        const float4 b2v = *((const float4*)(b2 + (size_t)kq * LLL) + t);
        #pragma unroll
        for (int r = 0; r < 16; r++) {
            const float4 mv = *((const float4*)(mask + (size_t)(l0 + r) * LLL) + t);
            acc[r][0] += b2v.x + mv.x;
            acc[r][1] += b2v.y + mv.y;
            acc[r][2] += b2v.z + mv.z;
            acc[r][3] += b2v.w + mv.w;
        }
    }

    // ---- softmax over m (row = full 1024 spread across 256 threads)
    float rowmax[16];
    #pragma unroll
    for (int r = 0; r < 16; r++) {
        float mx = fmaxf(fmaxf(acc[r][0], acc[r][1]), fmaxf(acc[r][2], acc[r][3]));
        #pragma unroll
        for (int o = 32; o > 0; o >>= 1) mx = fmaxf(mx, __shfl_xor(mx, o));
        if (lane == 0) wredm[wave][r] = mx;
    }
    __syncthreads();   // also guarantees all logits reads of hid_s are done
    #pragma unroll
    for (int r = 0; r < 16; r++)
        rowmax[r] = fmaxf(fmaxf(wredm[0][r], wredm[1][r]),
                          fmaxf(wredm[2][r], wredm[3][r]));
    #pragma unroll
    for (int r = 0; r < 16; r++) {
        float s = 0.f;
        #pragma unroll
        for (int j = 0; j < 4; j++) {
            acc[r][j] = __expf(acc[r][j] - rowmax[r]);
            s += acc[r][j];
        }
        #pragma unroll
        for (int o = 32; o > 0; o >>= 1) s += __shfl_xor(s, o);
        if (lane == 0) wreds[wave][r] = s;
    }
    // unnormalized probs -> LDS (reuse hid_s); 1/sum applied at the end
    #pragma unroll
    for (int r = 0; r < 16; r++) {
        float4 pv;
        pv.x = acc[r][0]; pv.y = acc[r][1]; pv.z = acc[r][2]; pv.w = acc[r][3];
        *(float4*)&hid_s[r * HHH + (t << 2)] = pv;
    }
    __syncthreads();

    // ---- P@V: wave w handles rows 4w..4w+3, lane = output channel j (0..63)
    const int w4 = wave << 2;
    float po[4] = {0.f, 0.f, 0.f, 0.f};
    const float* vb = proj + (size_t)bv * (2 * DD) + DD + kv * DHH + lane;
    for (int m = 0; m < LLL; m += 4) {
        const float v0 = vb[(size_t)(m + 0) * (BSZ * 2 * DD)];
        const float v1 = vb[(size_t)(m + 1) * (BSZ * 2 * DD)];
        const float v2 = vb[(size_t)(m + 2) * (BSZ * 2 * DD)];
        const float v3 = vb[(size_t)(m + 3) * (BSZ * 2 * DD)];
        #pragma unroll
        for (int r = 0; r < 4; r++) {
            const float4 pr = *(const float4*)&hid_s[(w4 + r) * HHH + m];
            po[r] = fmaf(pr.x, v0, po[r]);
            po[r] = fmaf(pr.y, v1, po[r]);
            po[r] = fmaf(pr.z, v2, po[r]);
            po[r] = fmaf(pr.w, v3, po[r]);
        }
    }
    #pragma unroll
    for (int r = 0; r < 4; r++) {
        const int row = w4 + r;
        const float s = wreds[0][row] + wreds[1][row] + wreds[2][row] + wreds[3][row];
        attn_out[(size_t)((l0 + row) * BSZ + bv) * DD + kv * DHH + lane] = po[r] / s;
    }
}

extern "C" void kernel_launch(void* const* d_in, const int* in_sizes, int n_in,
                              void* d_out, int out_size, void* d_ws, size_t ws_size,
                              hipStream_t stream)
{
    (void)in_sizes; (void)n_in; (void)out_size; (void)ws_size;
    const float* x  = (const float*)d_in[0];
    const float* am = (const float*)d_in[1];
    const float* Wi = (const float*)d_in[2];
    const float* bi = (const float*)d_in[3];
    const float* w1 = (const float*)d_in[4];
    const float* b1 = (const float*)d_in[5];
    const float* w2 = (const float*)d_in[6];
    const float* b2 = (const float*)d_in[7];
    const float* Wo = (const float*)d_in[8];
    const float* bo = (const float*)d_in[9];
    float* out = (float*)d_out;

    float* proj_ws = (float*)d_ws;                       // (4096, 2048) f32, 33.5 MB
    float* attn_ws = proj_ws + (size_t)4096 * 2048;      // (4096, 1024) f32, 16.8 MB

    // proj = x @ Wi.T + bi   (M=4096, N=2048, K=1024)
    gemm_nt_bias<<<dim3(64, 32), 256, 0, stream>>>(x, Wi, bi, proj_ws, 4096, 2048, 1024);
    // fused synthesizer attention (one block per (l-tile, p))
    attn_fused<<<dim3(64, 64), 256, 0, stream>>>(proj_ws, w1, b1, w2, b2, am, attn_ws);
    // out = attn @ Wo.T + bo (M=4096, N=1024, K=1024)
    gemm_nt_bias<<<dim3(64, 16), 256, 0, stream>>>(attn_ws, Wo, bo, out, 4096, 1024, 1024);
}

// Round 3
// 996.654 us; speedup vs baseline: 2.3800x; 2.3800x over previous
//
#include <hip/hip_runtime.h>

typedef unsigned short u16;
typedef short bf16x8 __attribute__((ext_vector_type(8)));
typedef float f32x4 __attribute__((ext_vector_type(4)));

#define BSZ 4
#define DD 1024
#define LLL 1024

__device__ __forceinline__ float bf2f(u16 u) {
    union { unsigned int i; float f; } w;
    w.i = ((unsigned int)u) << 16;
    return w.f;
}
__device__ __forceinline__ u16 f2bf(float f) {
    union { float fl; unsigned int i; } w;
    w.fl = f;
    w.i += 0x7fffu + ((w.i >> 16) & 1u);   // RNE
    return (u16)(w.i >> 16);
}

// ---- fp32 -> bf16 elementwise (n must be multiple of 1024; grid = n/1024)
__global__ void cvt_f32_bf16(const float* __restrict__ in, u16* __restrict__ out) {
    const size_t i = ((size_t)blockIdx.x * 256 + threadIdx.x) * 4;
    const float4 v = *(const float4*)(in + i);
    ushort4 o;
    o.x = f2bf(v.x); o.y = f2bf(v.y); o.z = f2bf(v.z); o.w = f2bf(v.w);
    *(ushort4*)(out + i) = o;
}

// ---- batched transpose+convert: in[z][R][C] f32 -> out[z][C][R] bf16
__global__ void transpose_cvt(const float* __restrict__ in, u16* __restrict__ out,
                              int R, int C) {
    __shared__ float tile[32][33];
    const size_t base = (size_t)blockIdx.z * R * C;
    const int c0 = blockIdx.x << 5, r0 = blockIdx.y << 5;
    const int tx = threadIdx.x & 31, ty = threadIdx.x >> 5;   // 256 thr = 32x8
    #pragma unroll
    for (int i = 0; i < 32; i += 8)
        tile[ty + i][tx] = in[base + (size_t)(r0 + ty + i) * C + c0 + tx];
    __syncthreads();
    #pragma unroll
    for (int i = 0; i < 32; i += 8)
        out[base + (size_t)(c0 + ty + i) * R + r0 + tx] = f2bf(tile[tx][ty + i]);
}

// ---- generic batched bf16 NT-GEMM: C[r][n] = sum_k A[r][k]*B[n][k] + bias[n]
// 128x128 tile, BK=32, 4 waves, 16x16x32 MFMA, fp32 acc.
// A: [z][M][lda] bf16 (batch stride sA elems), B: [z][N][ldb] bf16,
// bias fp32 (stride sBias), C bf16 or fp32 per OUT_F32. M,N from grid.
template<int OUT_F32, int RELU>
__global__ __launch_bounds__(256, 2) void gemm_bf16_nt(
    const u16* __restrict__ A, int lda, long long sA,
    const u16* __restrict__ B, int ldb, long long sB,
    const float* __restrict__ bias, int sBias,
    void* __restrict__ C, int ldc, long long sC,
    int K)
{
    __shared__ u16 As[128 * 32];
    __shared__ u16 Bs[128 * 32];
    const int t = threadIdx.x;
    const int z = blockIdx.z;
    const u16* Ab = A + (size_t)z * sA + (size_t)blockIdx.x * 128 * lda;
    const u16* Bb = B + (size_t)z * sB + (size_t)blockIdx.y * 128 * ldb;
    const int wave = t >> 6, lane = t & 63;
    const int wrow = (wave >> 1) << 6;   // 0 / 64
    const int wcol = (wave & 1) << 6;    // 0 / 64
    const int lr = lane & 15, lq = lane >> 4;
    const int srow = t >> 2;             // 0..63
    const int sk = (t & 3) << 3;         // 0,8,16,24 (elems)

    f32x4 acc[4][4];
    #pragma unroll
    for (int i = 0; i < 4; i++)
        #pragma unroll
        for (int j = 0; j < 4; j++)
            acc[i][j] = (f32x4){0.f, 0.f, 0.f, 0.f};

    for (int k0 = 0; k0 < K; k0 += 32) {
        const uint4 a0 = *(const uint4*)(Ab + (size_t)srow * lda + k0 + sk);
        const uint4 a1 = *(const uint4*)(Ab + (size_t)(srow + 64) * lda + k0 + sk);
        const uint4 b0 = *(const uint4*)(Bb + (size_t)srow * ldb + k0 + sk);
        const uint4 b1 = *(const uint4*)(Bb + (size_t)(srow + 64) * ldb + k0 + sk);
        __syncthreads();
        *(uint4*)&As[srow * 32 + sk] = a0;
        *(uint4*)&As[(srow + 64) * 32 + sk] = a1;
        *(uint4*)&Bs[srow * 32 + sk] = b0;
        *(uint4*)&Bs[(srow + 64) * 32 + sk] = b1;
        __syncthreads();
        bf16x8 af[4], bfv[4];
        #pragma unroll
        for (int i = 0; i < 4; i++)
            af[i] = *(const bf16x8*)&As[(wrow + i * 16 + lr) * 32 + lq * 8];
        #pragma unroll
        for (int j = 0; j < 4; j++)
            bfv[j] = *(const bf16x8*)&Bs[(wcol + j * 16 + lr) * 32 + lq * 8];
        #pragma unroll
        for (int i = 0; i < 4; i++)
            #pragma unroll
            for (int j = 0; j < 4; j++)
                acc[i][j] = __builtin_amdgcn_mfma_f32_16x16x32_bf16(
                    af[i], bfv[j], acc[i][j], 0, 0, 0);
    }

    // epilogue: C/D layout col=lane&15, row=quad*4+reg
    const float* biasb = bias + (size_t)z * sBias;
    const size_t row0 = (size_t)blockIdx.x * 128 + wrow + lq * 4;
    const int col0 = blockIdx.y * 128 + wcol + lr;
    #pragma unroll
    for (int j = 0; j < 4; j++) {
        const int col = col0 + j * 16;
        const float bb = biasb[col];
        #pragma unroll
        for (int i = 0; i < 4; i++) {
            #pragma unroll
            for (int r = 0; r < 4; r++) {
                float v = acc[i][j][r] + bb;
                if (RELU) v = fmaxf(v, 0.f);
                const size_t idx = (row0 + i * 16 + r) * (size_t)ldc + col;
                if (OUT_F32) ((float*)C)[(size_t)z * sC + idx] = v;
                else         ((u16*)C)[(size_t)z * sC + idx] = f2bf(v);
            }
        }
    }
}

// ---- softmax + P@V per (l-tile 16, p_local). logits already include b2.
// p decodes: logits side (kq, bq), v/output side (bv, kv).
__global__ __launch_bounds__(256, 2) void softmax_pv(
    const u16* __restrict__ logits,   // (2, 4096, 1024) bf16 for this head group
    const u16* __restrict__ proj,     // (4096, 2048) bf16; v = cols 1024..2047
    const float* __restrict__ mask,   // (1024, 1024) fp32
    u16* __restrict__ attn,           // (4096, 1024) bf16
    int g)
{
    __shared__ float ps[16 * 1024];
    __shared__ float wredm[4][16];
    __shared__ float wreds[4][16];
    const int t = threadIdx.x;
    const int l0 = blockIdx.x << 4;
    const int pl = blockIdx.y;            // 0..7
    const int kql = pl >> 2, bq = pl & 3;
    const int kq = 2 * g + kql;
    const int p = kq * 4 + bq;
    const int bv = p >> 4, kv = p & 15;
    const int lane = t & 63, wave = t >> 6;

    float acc[16][4];
    #pragma unroll
    for (int r = 0; r < 16; r++) {
        const ushort4 lv = *(const ushort4*)(logits + (size_t)kql * 4194304
                           + (size_t)((l0 + r) * BSZ + bq) * 1024 + (t << 2));
        const float4 mv = *(const float4*)(mask + (size_t)(l0 + r) * 1024 + (t << 2));
        acc[r][0] = bf2f(lv.x) + mv.x;
        acc[r][1] = bf2f(lv.y) + mv.y;
        acc[r][2] = bf2f(lv.z) + mv.z;
        acc[r][3] = bf2f(lv.w) + mv.w;
    }

    float rowmax[16];
    #pragma unroll
    for (int r = 0; r < 16; r++) {
        float mx = fmaxf(fmaxf(acc[r][0], acc[r][1]), fmaxf(acc[r][2], acc[r][3]));
        #pragma unroll
        for (int o = 32; o > 0; o >>= 1) mx = fmaxf(mx, __shfl_xor(mx, o));
        if (lane == 0) wredm[wave][r] = mx;
    }
    __syncthreads();
    #pragma unroll
    for (int r = 0; r < 16; r++)
        rowmax[r] = fmaxf(fmaxf(wredm[0][r], wredm[1][r]),
                          fmaxf(wredm[2][r], wredm[3][r]));
    #pragma unroll
    for (int r = 0; r < 16; r++) {
        float s = 0.f;
        #pragma unroll
        for (int j = 0; j < 4; j++) {
            acc[r][j] = __expf(acc[r][j] - rowmax[r]);
            s += acc[r][j];
        }
        #pragma unroll
        for (int o = 32; o > 0; o >>= 1) s += __shfl_xor(s, o);
        if (lane == 0) wreds[wave][r] = s;
    }
    #pragma unroll
    for (int r = 0; r < 16; r++) {
        float4 pv;
        pv.x = acc[r][0]; pv.y = acc[r][1]; pv.z = acc[r][2]; pv.w = acc[r][3];
        *(float4*)&ps[r * 1024 + (t << 2)] = pv;
    }
    __syncthreads();

    // P@V: wave w -> rows 4w..4w+3, lane -> channel (0..63)
    const int w4 = wave << 2;
    float po[4] = {0.f, 0.f, 0.f, 0.f};
    const u16* vb = proj + (size_t)bv * (2 * DD) + DD + kv * 64 + lane;
    for (int m = 0; m < LLL; m += 4) {
        const float v0 = bf2f(vb[(size_t)(m + 0) * (BSZ * 2 * DD)]);
        const float v1 = bf2f(vb[(size_t)(m + 1) * (BSZ * 2 * DD)]);
        const float v2 = bf2f(vb[(size_t)(m + 2) * (BSZ * 2 * DD)]);
        const float v3 = bf2f(vb[(size_t)(m + 3) * (BSZ * 2 * DD)]);
        #pragma unroll
        for (int r = 0; r < 4; r++) {
            const float4 pr = *(const float4*)&ps[(w4 + r) * 1024 + m];
            po[r] = fmaf(pr.x, v0, po[r]);
            po[r] = fmaf(pr.y, v1, po[r]);
            po[r] = fmaf(pr.z, v2, po[r]);
            po[r] = fmaf(pr.w, v3, po[r]);
        }
    }
    #pragma unroll
    for (int r = 0; r < 4; r++) {
        const int row = w4 + r;
        const float s = wreds[0][row] + wreds[1][row] + wreds[2][row] + wreds[3][row];
        attn[(size_t)((l0 + row) * BSZ + bv) * DD + kv * 64 + lane] = f2bf(po[r] / s);
    }
}

extern "C" void kernel_launch(void* const* d_in, const int* in_sizes, int n_in,
                              void* d_out, int out_size, void* d_ws, size_t ws_size,
                              hipStream_t stream)
{
    (void)in_sizes; (void)n_in; (void)out_size; (void)ws_size;
    const float* x  = (const float*)d_in[0];
    const float* am = (const float*)d_in[1];
    const float* Wi = (const float*)d_in[2];
    const float* bi = (const float*)d_in[3];
    const float* w1 = (const float*)d_in[4];
    const float* b1 = (const float*)d_in[5];
    const float* w2 = (const float*)d_in[6];
    const float* b2 = (const float*)d_in[7];
    const float* Wo = (const float*)d_in[8];
    const float* bo = (const float*)d_in[9];

    // ws layout (elems, bf16): total 52M elems = 104 MB
    u16* x_b    = (u16*)d_ws;                  // 4096x1024      = 4M
    u16* Wi_b   = x_b    + (size_t)4194304;    // 2048x1024      = 2M
    u16* w1t    = Wi_b   + (size_t)2097152;    // 16 x 1024x64   = 1M
    u16* w2t    = w1t    + (size_t)1048576;    // 16 x 1024x1024 = 16M
    u16* Wo_b   = w2t    + (size_t)16777216;   // 1024x1024      = 1M
    u16* proj_b = Wo_b   + (size_t)1048576;    // 4096x2048      = 8M
    u16* attn_b = proj_b + (size_t)8388608;    // 4096x1024      = 4M
    u16* hid_g  = attn_b + (size_t)4194304;    // 2 x 4096x1024  = 8M
    u16* logit_g= hid_g  + (size_t)8388608;    // 2 x 4096x1024  = 8M

    // ---- prep: converts + transposes
    cvt_f32_bf16<<<4096, 256, 0, stream>>>(x,  x_b);
    cvt_f32_bf16<<<2048, 256, 0, stream>>>(Wi, Wi_b);
    cvt_f32_bf16<<<1024, 256, 0, stream>>>(Wo, Wo_b);
    transpose_cvt<<<dim3(32,  2, 16), 256, 0, stream>>>(w1, w1t, 64,   1024);
    transpose_cvt<<<dim3(32, 32, 16), 256, 0, stream>>>(w2, w2t, 1024, 1024);

    // ---- proj = x @ Wi.T + bi  -> bf16 (4096 x 2048)
    gemm_bf16_nt<0, 0><<<dim3(32, 16, 1), 256, 0, stream>>>(
        x_b, 1024, 0, Wi_b, 1024, 0, bi, 0, (void*)proj_b, 2048, 0, 1024);

    // ---- per head-group (2 heads): hid -> logits -> softmax+PV
    for (int g = 0; g < 8; g++) {
        // hid = relu(q @ w1t.T + b1): M=4096, N=1024, K=64, z=2 heads
        gemm_bf16_nt<0, 1><<<dim3(32, 8, 2), 256, 0, stream>>>(
            proj_b + (size_t)g * 128, 2048, 64,
            w1t + (size_t)g * 2 * 65536, 64, 65536,
            b1 + (size_t)g * 2 * 1024, 1024,
            (void*)hid_g, 1024, 4194304, 64);
        // logits = hid @ w2t.T + b2: M=4096, N=1024, K=1024, z=2 heads
        gemm_bf16_nt<0, 0><<<dim3(32, 8, 2), 256, 0, stream>>>(
            hid_g, 1024, 4194304,
            w2t + (size_t)g * 2 * 1048576, 1024, 1048576,
            b2 + (size_t)g * 2 * 1024, 1024,
            (void*)logit_g, 1024, 4194304, 1024);
        // softmax + P@V for the 8 p-values of this group
        softmax_pv<<<dim3(64, 8), 256, 0, stream>>>(logit_g, proj_b, am, attn_b, g);
    }

    // ---- out = attn @ Wo.T + bo -> fp32 (4096 x 1024)
    gemm_bf16_nt<1, 0><<<dim3(32, 8, 1), 256, 0, stream>>>(
        attn_b, 1024, 0, Wo_b, 1024, 0, bo, 0, d_out, 1024, 0, 1024);
}

// Round 4
// 666.490 us; speedup vs baseline: 3.5590x; 1.4954x over previous
//
#include <hip/hip_runtime.h>

typedef unsigned short u16;
typedef short bf16x8 __attribute__((ext_vector_type(8)));
typedef float f32x4 __attribute__((ext_vector_type(4)));

#define BSZ 4
#define DD 1024
#define LLL 1024

__device__ __forceinline__ float bf2f(u16 u) {
    union { unsigned int i; float f; } w;
    w.i = ((unsigned int)u) << 16;
    return w.f;
}
__device__ __forceinline__ u16 f2bf(float f) {
    union { float fl; unsigned int i; } w;
    w.fl = f;
    w.i += 0x7fffu + ((w.i >> 16) & 1u);   // RNE
    return (u16)(w.i >> 16);
}

// ---- fp32 -> bf16 elementwise (grid = n/1024)
__global__ void cvt_f32_bf16(const float* __restrict__ in, u16* __restrict__ out) {
    const size_t i = ((size_t)blockIdx.x * 256 + threadIdx.x) * 4;
    const float4 v = *(const float4*)(in + i);
    ushort4 o;
    o.x = f2bf(v.x); o.y = f2bf(v.y); o.z = f2bf(v.z); o.w = f2bf(v.w);
    *(ushort4*)(out + i) = o;
}

// ---- batched transpose+convert: in[z][R][C] f32 -> out[z][C][R] bf16
__global__ void transpose_cvt(const float* __restrict__ in, u16* __restrict__ out,
                              int R, int C) {
    __shared__ float tile[32][33];
    const size_t base = (size_t)blockIdx.z * R * C;
    const int c0 = blockIdx.x << 5, r0 = blockIdx.y << 5;
    const int tx = threadIdx.x & 31, ty = threadIdx.x >> 5;   // 256 thr = 32x8
    #pragma unroll
    for (int i = 0; i < 32; i += 8)
        tile[ty + i][tx] = in[base + (size_t)(r0 + ty + i) * C + c0 + tx];
    __syncthreads();
    #pragma unroll
    for (int i = 0; i < 32; i += 8)
        out[base + (size_t)(c0 + ty + i) * R + r0 + tx] = f2bf(tile[tx][ty + i]);
}

// ---- build vt[j][d][m] (j = b*16+k) from proj's v-half: vt[j*64+d][m] bf16.
// 64x64 tile transpose per block; grid (16 m-tiles, 64 j).
__global__ void build_vt(const u16* __restrict__ proj, u16* __restrict__ vt) {
    __shared__ u16 tile[64][66];
    const int t = threadIdx.x;
    const int m0 = blockIdx.x << 6;
    const int jj = blockIdx.y;
    const int b = jj >> 4, k = jj & 15;
    const int tx = t & 63, ty = t >> 6;
    #pragma unroll
    for (int mi = ty; mi < 64; mi += 4)
        tile[mi][tx] = proj[(size_t)((m0 + mi) * BSZ + b) * 2048 + 1024 + k * 64 + tx];
    __syncthreads();
    #pragma unroll
    for (int di = ty; di < 64; di += 4)
        vt[((size_t)jj * 64 + di) * 1024 + m0 + tx] = tile[tx][di];
}

// ---- generic batched bf16 NT-GEMM: C[r][n] = sum_k A[r][k]*B[n][k] + bias[n]
// 128x128 tile, BK=32, 4 waves, 16x16x32 MFMA, fp32 acc.
// MASKADD: += mask[(row>>2)*1024 + col] in epilogue (fp32 mask).
template<int OUT_F32, int RELU, int MASKADD>
__global__ __launch_bounds__(256, 2) void gemm_bf16_nt(
    const u16* __restrict__ A, int lda, long long sA,
    const u16* __restrict__ B, int ldb, long long sB,
    const float* __restrict__ bias, int sBias,
    const float* __restrict__ mask,
    void* __restrict__ C, int ldc, long long sC,
    int K)
{
    __shared__ u16 As[128 * 32];
    __shared__ u16 Bs[128 * 32];
    const int t = threadIdx.x;
    const int z = blockIdx.z;
    const u16* Ab = A + (size_t)z * sA + (size_t)blockIdx.x * 128 * lda;
    const u16* Bb = B + (size_t)z * sB + (size_t)blockIdx.y * 128 * ldb;
    const int wave = t >> 6, lane = t & 63;
    const int wrow = (wave >> 1) << 6;   // 0 / 64
    const int wcol = (wave & 1) << 6;    // 0 / 64
    const int lr = lane & 15, lq = lane >> 4;
    const int srow = t >> 2;             // 0..63
    const int sk = (t & 3) << 3;         // 0,8,16,24 (elems)

    f32x4 acc[4][4];
    #pragma unroll
    for (int i = 0; i < 4; i++)
        #pragma unroll
        for (int j = 0; j < 4; j++)
            acc[i][j] = (f32x4){0.f, 0.f, 0.f, 0.f};

    for (int k0 = 0; k0 < K; k0 += 32) {
        const uint4 a0 = *(const uint4*)(Ab + (size_t)srow * lda + k0 + sk);
        const uint4 a1 = *(const uint4*)(Ab + (size_t)(srow + 64) * lda + k0 + sk);
        const uint4 b0 = *(const uint4*)(Bb + (size_t)srow * ldb + k0 + sk);
        const uint4 b1 = *(const uint4*)(Bb + (size_t)(srow + 64) * ldb + k0 + sk);
        __syncthreads();
        *(uint4*)&As[srow * 32 + sk] = a0;
        *(uint4*)&As[(srow + 64) * 32 + sk] = a1;
        *(uint4*)&Bs[srow * 32 + sk] = b0;
        *(uint4*)&Bs[(srow + 64) * 32 + sk] = b1;
        __syncthreads();
        bf16x8 af[4], bfv[4];
        #pragma unroll
        for (int i = 0; i < 4; i++)
            af[i] = *(const bf16x8*)&As[(wrow + i * 16 + lr) * 32 + lq * 8];
        #pragma unroll
        for (int j = 0; j < 4; j++)
            bfv[j] = *(const bf16x8*)&Bs[(wcol + j * 16 + lr) * 32 + lq * 8];
        #pragma unroll
        for (int i = 0; i < 4; i++)
            #pragma unroll
            for (int j = 0; j < 4; j++)
                acc[i][j] = __builtin_amdgcn_mfma_f32_16x16x32_bf16(
                    af[i], bfv[j], acc[i][j], 0, 0, 0);
    }

    // epilogue: C/D layout col=lane&15, row=quad*4+reg
    const float* biasb = bias + (size_t)z * sBias;
    const size_t row0 = (size_t)blockIdx.x * 128 + wrow + lq * 4;
    const int col0 = blockIdx.y * 128 + wcol + lr;
    #pragma unroll
    for (int j = 0; j < 4; j++) {
        const int col = col0 + j * 16;
        const float bb = biasb[col];
        #pragma unroll
        for (int i = 0; i < 4; i++) {
            #pragma unroll
            for (int r = 0; r < 4; r++) {
                const size_t row = row0 + i * 16 + r;
                float v = acc[i][j][r] + bb;
                if (MASKADD) v += mask[(row >> 2) * (size_t)1024 + col];
                if (RELU) v = fmaxf(v, 0.f);
                const size_t idx = row * (size_t)ldc + col;
                if (OUT_F32) ((float*)C)[(size_t)z * sC + idx] = v;
                else         ((u16*)C)[(size_t)z * sC + idx] = f2bf(v);
            }
        }
    }
}

// ---- softmax (logits already masked+biased) + MFMA P@V per (16-row l-tile, p_local)
__global__ __launch_bounds__(256, 4) void softmax_pv(
    const u16* __restrict__ logits,   // (2, 4096, 1024) bf16, masked
    const u16* __restrict__ vt,       // (64, 64, 1024) bf16: [j=b*16+k][d][m]
    u16* __restrict__ attn,           // (4096, 1024) bf16
    int g)
{
    __shared__ u16 ps[16 * 1032];     // probs bf16, row-padded (+8) vs bank conflicts
    __shared__ float wredm[4][16];
    __shared__ float wreds[4][16];
    const int t = threadIdx.x;
    const int l0 = blockIdx.x << 4;
    const int pl = blockIdx.y;            // 0..7
    const int kql = pl >> 2, bq = pl & 3;
    const int kq = 2 * g + kql;
    const int p = kq * 4 + bq;
    const int bv = p >> 4, kv = p & 15;
    const int jv = bv * 16 + kv;          // v's batch index
    const int lane = t & 63, wave = t >> 6;

    float acc[16][4];
    #pragma unroll
    for (int r = 0; r < 16; r++) {
        const ushort4 lv = *(const ushort4*)(logits + (size_t)kql * 4194304
                           + (size_t)((l0 + r) * BSZ + bq) * 1024 + (t << 2));
        acc[r][0] = bf2f(lv.x);
        acc[r][1] = bf2f(lv.y);
        acc[r][2] = bf2f(lv.z);
        acc[r][3] = bf2f(lv.w);
    }

    float rowmax[16];
    #pragma unroll
    for (int r = 0; r < 16; r++) {
        float mx = fmaxf(fmaxf(acc[r][0], acc[r][1]), fmaxf(acc[r][2], acc[r][3]));
        #pragma unroll
        for (int o = 32; o > 0; o >>= 1) mx = fmaxf(mx, __shfl_xor(mx, o));
        if (lane == 0) wredm[wave][r] = mx;
    }
    __syncthreads();
    #pragma unroll
    for (int r = 0; r < 16; r++)
        rowmax[r] = fmaxf(fmaxf(wredm[0][r], wredm[1][r]),
                          fmaxf(wredm[2][r], wredm[3][r]));
    #pragma unroll
    for (int r = 0; r < 16; r++) {
        float s = 0.f;
        #pragma unroll
        for (int jj = 0; jj < 4; jj++) {
            acc[r][jj] = __expf(acc[r][jj] - rowmax[r]);
            s += acc[r][jj];
        }
        #pragma unroll
        for (int o = 32; o > 0; o >>= 1) s += __shfl_xor(s, o);
        if (lane == 0) wreds[wave][r] = s;
    }
    // unnormalized probs (<=1) -> LDS bf16; 1/sum applied in epilogue
    #pragma unroll
    for (int r = 0; r < 16; r++) {
        ushort4 pv;
        pv.x = f2bf(acc[r][0]); pv.y = f2bf(acc[r][1]);
        pv.z = f2bf(acc[r][2]); pv.w = f2bf(acc[r][3]);
        *(ushort4*)&ps[r * 1032 + (t << 2)] = pv;
    }
    __syncthreads();

    // P@V via MFMA: wave handles d in [wave*16, wave*16+16), 16 rows
    const int lr = lane & 15, lq = lane >> 4;
    f32x4 po = (f32x4){0.f, 0.f, 0.f, 0.f};
    const u16* vb = vt + ((size_t)jv * 64 + wave * 16 + lr) * 1024 + lq * 8;
    const u16* pb = &ps[lr * 1032 + lq * 8];
    for (int k0 = 0; k0 < 1024; k0 += 32) {
        const bf16x8 a = *(const bf16x8*)(pb + k0);
        const bf16x8 b = *(const bf16x8*)(vb + k0);
        po = __builtin_amdgcn_mfma_f32_16x16x32_bf16(a, b, po, 0, 0, 0);
    }
    #pragma unroll
    for (int ri = 0; ri < 4; ri++) {
        const int row = lq * 4 + ri;
        const float s = wreds[0][row] + wreds[1][row] + wreds[2][row] + wreds[3][row];
        attn[(size_t)((l0 + row) * BSZ + bv) * DD + kv * 64 + wave * 16 + lr] =
            f2bf(po[ri] / s);
    }
}

extern "C" void kernel_launch(void* const* d_in, const int* in_sizes, int n_in,
                              void* d_out, int out_size, void* d_ws, size_t ws_size,
                              hipStream_t stream)
{
    (void)in_sizes; (void)n_in; (void)out_size; (void)ws_size;
    const float* x  = (const float*)d_in[0];
    const float* am = (const float*)d_in[1];
    const float* Wi = (const float*)d_in[2];
    const float* bi = (const float*)d_in[3];
    const float* w1 = (const float*)d_in[4];
    const float* b1 = (const float*)d_in[5];
    const float* w2 = (const float*)d_in[6];
    const float* b2 = (const float*)d_in[7];
    const float* Wo = (const float*)d_in[8];
    const float* bo = (const float*)d_in[9];

    // ws layout (elems, bf16): 52M elems = 104 MB (round-3-proven size)
    u16* x_b    = (u16*)d_ws;                  // 4096x1024      = 4M
    u16* Wi_b   = x_b    + (size_t)4194304;    // 2048x1024      = 2M
    u16* w1t    = Wi_b   + (size_t)2097152;    // 16 x 1024x64   = 1M
    u16* w2t    = w1t    + (size_t)1048576;    // 16 x 1024x1024 = 16M
    u16* Wo_b   = w2t    + (size_t)16777216;   // 1024x1024      = 1M
    u16* proj_b = Wo_b   + (size_t)1048576;    // 4096x2048      = 8M
    u16* attn_b = proj_b + (size_t)8388608;    // 4096x1024      = 4M
    u16* hid_g  = attn_b + (size_t)4194304;    // 2 x 4096x1024  = 8M
    u16* logit_g= hid_g  + (size_t)8388608;    // 2 x 4096x1024  = 8M
    u16* vt     = x_b;   // alias: x_b is dead after the proj GEMM

    // ---- prep: converts + transposes
    cvt_f32_bf16<<<4096, 256, 0, stream>>>(x,  x_b);
    cvt_f32_bf16<<<2048, 256, 0, stream>>>(Wi, Wi_b);
    cvt_f32_bf16<<<1024, 256, 0, stream>>>(Wo, Wo_b);
    transpose_cvt<<<dim3(32,  2, 16), 256, 0, stream>>>(w1, w1t, 64,   1024);
    transpose_cvt<<<dim3(32, 32, 16), 256, 0, stream>>>(w2, w2t, 1024, 1024);

    // ---- proj = x @ Wi.T + bi  -> bf16 (4096 x 2048)
    gemm_bf16_nt<0, 0, 0><<<dim3(32, 16, 1), 256, 0, stream>>>(
        x_b, 1024, 0, Wi_b, 1024, 0, bi, 0, nullptr,
        (void*)proj_b, 2048, 0, 1024);

    // ---- vt[j][d][m] from proj's v-half (overwrites x_b)
    build_vt<<<dim3(16, 64), 256, 0, stream>>>(proj_b, vt);

    // ---- per head-group (2 heads): hid -> logits(+mask) -> softmax+PV
    for (int g = 0; g < 8; g++) {
        // hid = relu(q @ w1t.T + b1): M=4096, N=1024, K=64, z=2 heads
        gemm_bf16_nt<0, 1, 0><<<dim3(32, 8, 2), 256, 0, stream>>>(
            proj_b + (size_t)g * 128, 2048, 64,
            w1t + (size_t)g * 2 * 65536, 64, 65536,
            b1 + (size_t)g * 2 * 1024, 1024, nullptr,
            (void*)hid_g, 1024, 4194304, 64);
        // logits = hid @ w2t.T + b2 + mask: M=4096, N=1024, K=1024, z=2 heads
        gemm_bf16_nt<0, 0, 1><<<dim3(32, 8, 2), 256, 0, stream>>>(
            hid_g, 1024, 4194304,
            w2t + (size_t)g * 2 * 1048576, 1024, 1048576,
            b2 + (size_t)g * 2 * 1024, 1024, am,
            (void*)logit_g, 1024, 4194304, 1024);
        // softmax + MFMA P@V for the 8 p-values of this group
        softmax_pv<<<dim3(64, 8), 256, 0, stream>>>(logit_g, vt, attn_b, g);
    }

    // ---- out = attn @ Wo.T + bo -> fp32 (4096 x 1024)
    gemm_bf16_nt<1, 0, 0><<<dim3(32, 8, 1), 256, 0, stream>>>(
        attn_b, 1024, 0, Wo_b, 1024, 0, bo, 0, nullptr,
        d_out, 1024, 0, 1024);
}

// Round 5
// 563.684 us; speedup vs baseline: 4.2080x; 1.1824x over previous
//
#include <hip/hip_runtime.h>

typedef unsigned short u16;
typedef short bf16x8 __attribute__((ext_vector_type(8)));
typedef float f32x4 __attribute__((ext_vector_type(4)));

#define BSZ 4
#define DD 1024
#define LLL 1024

__device__ __forceinline__ float bf2f(u16 u) {
    union { unsigned int i; float f; } w;
    w.i = ((unsigned int)u) << 16;
    return w.f;
}
__device__ __forceinline__ u16 f2bf(float f) {
    union { float fl; unsigned int i; } w;
    w.fl = f;
    w.i += 0x7fffu + ((w.i >> 16) & 1u);   // RNE
    return (u16)(w.i >> 16);
}

// async global->LDS, 16B per lane; LDS dst must be wave-uniform base + lane*16
__device__ __forceinline__ void load_lds16(const u16* g, u16* l) {
    __builtin_amdgcn_global_load_lds(
        (const __attribute__((address_space(1))) unsigned int*)g,
        (__attribute__((address_space(3))) unsigned int*)l, 16, 0, 0);
}

// ---- fp32 -> bf16 elementwise (grid = n/1024)
__global__ void cvt_f32_bf16(const float* __restrict__ in, u16* __restrict__ out) {
    const size_t i = ((size_t)blockIdx.x * 256 + threadIdx.x) * 4;
    const float4 v = *(const float4*)(in + i);
    ushort4 o;
    o.x = f2bf(v.x); o.y = f2bf(v.y); o.z = f2bf(v.z); o.w = f2bf(v.w);
    *(ushort4*)(out + i) = o;
}

// ---- batched transpose+convert: in[z][R][C] f32 -> out[z][C][R] bf16
__global__ void transpose_cvt(const float* __restrict__ in, u16* __restrict__ out,
                              int R, int C) {
    __shared__ float tile[32][33];
    const size_t base = (size_t)blockIdx.z * R * C;
    const int c0 = blockIdx.x << 5, r0 = blockIdx.y << 5;
    const int tx = threadIdx.x & 31, ty = threadIdx.x >> 5;   // 256 thr = 32x8
    #pragma unroll
    for (int i = 0; i < 32; i += 8)
        tile[ty + i][tx] = in[base + (size_t)(r0 + ty + i) * C + c0 + tx];
    __syncthreads();
    #pragma unroll
    for (int i = 0; i < 32; i += 8)
        out[base + (size_t)(c0 + ty + i) * R + r0 + tx] = f2bf(tile[tx][ty + i]);
}

// ---- build vt[j][d][m] (j = b*16+k) from proj's v-half
__global__ void build_vt(const u16* __restrict__ proj, u16* __restrict__ vt) {
    __shared__ u16 tile[64][66];
    const int t = threadIdx.x;
    const int m0 = blockIdx.x << 6;
    const int jj = blockIdx.y;
    const int b = jj >> 4, k = jj & 15;
    const int tx = t & 63, ty = t >> 6;
    #pragma unroll
    for (int mi = ty; mi < 64; mi += 4)
        tile[mi][tx] = proj[(size_t)((m0 + mi) * BSZ + b) * 2048 + 1024 + k * 64 + tx];
    __syncthreads();
    #pragma unroll
    for (int di = ty; di < 64; di += 4)
        vt[((size_t)jj * 64 + di) * 1024 + m0 + tx] = tile[tx][di];
}

// ---- generic batched bf16 NT-GEMM: C[r][n] = sum_k A[r][k]*B[n][k] + bias[n]
// 128x128 tile, BK=32, 4 waves, 16x16x32 MFMA, fp32 acc.
// Staging via global_load_lds width=16 (m97 technique).
template<int OUT_F32, int RELU, int MASKADD>
__global__ __launch_bounds__(256, 2) void gemm_bf16_nt(
    const u16* __restrict__ A, int lda, long long sA,
    const u16* __restrict__ B, int ldb, long long sB,
    const float* __restrict__ bias, int sBias,
    const float* __restrict__ mask,
    void* __restrict__ C, int ldc, long long sC,
    int K)
{
    __shared__ u16 As[128 * 32];
    __shared__ u16 Bs[128 * 32];
    const int t = threadIdx.x;
    const int z = blockIdx.z;
    const u16* Ab = A + (size_t)z * sA + (size_t)blockIdx.x * 128 * lda;
    const u16* Bb = B + (size_t)z * sB + (size_t)blockIdx.y * 128 * ldb;
    const int wave = t >> 6, lane = t & 63;
    const int wrow = (wave >> 1) << 6;   // 0 / 64
    const int wcol = (wave & 1) << 6;    // 0 / 64
    const int lr = lane & 15, lq = lane >> 4;
    const int srow = t >> 2;             // 0..63
    const int sk = (t & 3) << 3;         // 0,8,16,24 (elems)

    // global srcs (per-lane) and LDS dsts: LDS byte offset is exactly 16*t
    const u16* Ap0 = Ab + (size_t)srow * lda + sk;
    const u16* Ap1 = Ab + (size_t)(srow + 64) * lda + sk;
    const u16* Bp0 = Bb + (size_t)srow * ldb + sk;
    const u16* Bp1 = Bb + (size_t)(srow + 64) * ldb + sk;
    u16* As0 = &As[t * 8];
    u16* As1 = &As[2048 + t * 8];
    u16* Bs0 = &Bs[t * 8];
    u16* Bs1 = &Bs[2048 + t * 8];

    f32x4 acc[4][4];
    #pragma unroll
    for (int i = 0; i < 4; i++)
        #pragma unroll
        for (int j = 0; j < 4; j++)
            acc[i][j] = (f32x4){0.f, 0.f, 0.f, 0.f};

    for (int k0 = 0; k0 < K; k0 += 32) {
        __syncthreads();                 // prior reads of As/Bs complete
        load_lds16(Ap0 + k0, As0);
        load_lds16(Ap1 + k0, As1);
        load_lds16(Bp0 + k0, Bs0);
        load_lds16(Bp1 + k0, Bs1);
        __syncthreads();                 // compiler drains vmcnt before barrier
        bf16x8 af[4], bfv[4];
        #pragma unroll
        for (int i = 0; i < 4; i++)
            af[i] = *(const bf16x8*)&As[(wrow + i * 16 + lr) * 32 + lq * 8];
        #pragma unroll
        for (int j = 0; j < 4; j++)
            bfv[j] = *(const bf16x8*)&Bs[(wcol + j * 16 + lr) * 32 + lq * 8];
        #pragma unroll
        for (int i = 0; i < 4; i++)
            #pragma unroll
            for (int j = 0; j < 4; j++)
                acc[i][j] = __builtin_amdgcn_mfma_f32_16x16x32_bf16(
                    af[i], bfv[j], acc[i][j], 0, 0, 0);
    }

    // epilogue: C/D layout col=lane&15, row=quad*4+reg
    const float* biasb = bias + (size_t)z * sBias;
    const size_t row0 = (size_t)blockIdx.x * 128 + wrow + lq * 4;
    const int col0 = blockIdx.y * 128 + wcol + lr;
    #pragma unroll
    for (int j = 0; j < 4; j++) {
        const int col = col0 + j * 16;
        const float bb = biasb[col];
        #pragma unroll
        for (int i = 0; i < 4; i++) {
            #pragma unroll
            for (int r = 0; r < 4; r++) {
                const size_t row = row0 + i * 16 + r;
                float v = acc[i][j][r] + bb;
                if (MASKADD) v += mask[(row >> 2) * (size_t)1024 + col];
                if (RELU) v = fmaxf(v, 0.f);
                const size_t idx = row * (size_t)ldc + col;
                if (OUT_F32) ((float*)C)[(size_t)z * sC + idx] = v;
                else         ((u16*)C)[(size_t)z * sC + idx] = f2bf(v);
            }
        }
    }
}

// ---- softmax (logits already masked+biased) + MFMA P@V per (16-row l-tile, p_local)
// group of 4 heads: pl in [0,16), kql = pl>>2, bq = pl&3
__global__ __launch_bounds__(256, 4) void softmax_pv(
    const u16* __restrict__ logits,   // (4, 4096, 1024) bf16, masked
    const u16* __restrict__ vt,       // (64, 64, 1024) bf16: [j=b*16+k][d][m]
    u16* __restrict__ attn,           // (4096, 1024) bf16
    int g)
{
    __shared__ u16 ps[16 * 1032];
    __shared__ float wredm[4][16];
    __shared__ float wreds[4][16];
    const int t = threadIdx.x;
    const int l0 = blockIdx.x << 4;
    const int pl = blockIdx.y;            // 0..15
    const int kql = pl >> 2, bq = pl & 3;
    const int kq = 4 * g + kql;
    const int p = kq * 4 + bq;
    const int bv = p >> 4, kv = p & 15;
    const int jv = bv * 16 + kv;
    const int lane = t & 63, wave = t >> 6;

    float acc[16][4];
    #pragma unroll
    for (int r = 0; r < 16; r++) {
        const ushort4 lv = *(const ushort4*)(logits + (size_t)kql * 4194304
                           + (size_t)((l0 + r) * BSZ + bq) * 1024 + (t << 2));
        acc[r][0] = bf2f(lv.x);
        acc[r][1] = bf2f(lv.y);
        acc[r][2] = bf2f(lv.z);
        acc[r][3] = bf2f(lv.w);
    }

    float rowmax[16];
    #pragma unroll
    for (int r = 0; r < 16; r++) {
        float mx = fmaxf(fmaxf(acc[r][0], acc[r][1]), fmaxf(acc[r][2], acc[r][3]));
        #pragma unroll
        for (int o = 32; o > 0; o >>= 1) mx = fmaxf(mx, __shfl_xor(mx, o));
        if (lane == 0) wredm[wave][r] = mx;
    }
    __syncthreads();
    #pragma unroll
    for (int r = 0; r < 16; r++)
        rowmax[r] = fmaxf(fmaxf(wredm[0][r], wredm[1][r]),
                          fmaxf(wredm[2][r], wredm[3][r]));
    #pragma unroll
    for (int r = 0; r < 16; r++) {
        float s = 0.f;
        #pragma unroll
        for (int jj = 0; jj < 4; jj++) {
            acc[r][jj] = __expf(acc[r][jj] - rowmax[r]);
            s += acc[r][jj];
        }
        #pragma unroll
        for (int o = 32; o > 0; o >>= 1) s += __shfl_xor(s, o);
        if (lane == 0) wreds[wave][r] = s;
    }
    #pragma unroll
    for (int r = 0; r < 16; r++) {
        ushort4 pv;
        pv.x = f2bf(acc[r][0]); pv.y = f2bf(acc[r][1]);
        pv.z = f2bf(acc[r][2]); pv.w = f2bf(acc[r][3]);
        *(ushort4*)&ps[r * 1032 + (t << 2)] = pv;
    }
    __syncthreads();

    // P@V via MFMA: wave handles d in [wave*16, wave*16+16)
    const int lr = lane & 15, lq = lane >> 4;
    f32x4 po = (f32x4){0.f, 0.f, 0.f, 0.f};
    const u16* vb = vt + ((size_t)jv * 64 + wave * 16 + lr) * 1024 + lq * 8;
    const u16* pb = &ps[lr * 1032 + lq * 8];
    for (int k0 = 0; k0 < 1024; k0 += 32) {
        const bf16x8 a = *(const bf16x8*)(pb + k0);
        const bf16x8 b = *(const bf16x8*)(vb + k0);
        po = __builtin_amdgcn_mfma_f32_16x16x32_bf16(a, b, po, 0, 0, 0);
    }
    #pragma unroll
    for (int ri = 0; ri < 4; ri++) {
        const int row = lq * 4 + ri;
        const float s = wreds[0][row] + wreds[1][row] + wreds[2][row] + wreds[3][row];
        attn[(size_t)((l0 + row) * BSZ + bv) * DD + kv * 64 + wave * 16 + lr] =
            f2bf(po[ri] / s);
    }
}

extern "C" void kernel_launch(void* const* d_in, const int* in_sizes, int n_in,
                              void* d_out, int out_size, void* d_ws, size_t ws_size,
                              hipStream_t stream)
{
    (void)in_sizes; (void)n_in; (void)out_size; (void)ws_size;
    const float* x  = (const float*)d_in[0];
    const float* am = (const float*)d_in[1];
    const float* Wi = (const float*)d_in[2];
    const float* bi = (const float*)d_in[3];
    const float* w1 = (const float*)d_in[4];
    const float* b1 = (const float*)d_in[5];
    const float* w2 = (const float*)d_in[6];
    const float* b2 = (const float*)d_in[7];
    const float* Wo = (const float*)d_in[8];
    const float* bo = (const float*)d_in[9];

    // ws layout (elems, bf16): 68M elems = 136 MB (ws_size = 256 MiB per
    // round-4 fillBuffer WRITE_SIZE = 268435456 B)
    u16* x_b    = (u16*)d_ws;                  // 4096x1024      = 4M
    u16* Wi_b   = x_b    + (size_t)4194304;    // 2048x1024      = 2M
    u16* w1t    = Wi_b   + (size_t)2097152;    // 16 x 1024x64   = 1M
    u16* w2t    = w1t    + (size_t)1048576;    // 16 x 1024x1024 = 16M
    u16* Wo_b   = w2t    + (size_t)16777216;   // 1024x1024      = 1M
    u16* proj_b = Wo_b   + (size_t)1048576;    // 4096x2048      = 8M
    u16* attn_b = proj_b + (size_t)8388608;    // 4096x1024      = 4M
    u16* hid_g  = attn_b + (size_t)4194304;    // 4 x 4096x1024  = 16M
    u16* logit_g= hid_g  + (size_t)16777216;   // 4 x 4096x1024  = 16M
    u16* vt     = x_b;   // alias: x_b dead after proj GEMM

    // ---- prep
    cvt_f32_bf16<<<4096, 256, 0, stream>>>(x,  x_b);
    cvt_f32_bf16<<<2048, 256, 0, stream>>>(Wi, Wi_b);
    cvt_f32_bf16<<<1024, 256, 0, stream>>>(Wo, Wo_b);
    transpose_cvt<<<dim3(32,  2, 16), 256, 0, stream>>>(w1, w1t, 64,   1024);
    transpose_cvt<<<dim3(32, 32, 16), 256, 0, stream>>>(w2, w2t, 1024, 1024);

    // ---- proj = x @ Wi.T + bi  -> bf16 (4096 x 2048)
    gemm_bf16_nt<0, 0, 0><<<dim3(32, 16, 1), 256, 0, stream>>>(
        x_b, 1024, 0, Wi_b, 1024, 0, bi, 0, nullptr,
        (void*)proj_b, 2048, 0, 1024);

    // ---- vt[j][d][m] from proj's v-half (overwrites x_b)
    build_vt<<<dim3(16, 64), 256, 0, stream>>>(proj_b, vt);

    // ---- per head-group (4 heads): hid -> logits(+mask) -> softmax+PV
    for (int g = 0; g < 4; g++) {
        gemm_bf16_nt<0, 1, 0><<<dim3(32, 8, 4), 256, 0, stream>>>(
            proj_b + (size_t)g * 256, 2048, 64,
            w1t + (size_t)g * 4 * 65536, 64, 65536,
            b1 + (size_t)g * 4 * 1024, 1024, nullptr,
            (void*)hid_g, 1024, 4194304, 64);
        gemm_bf16_nt<0, 0, 1><<<dim3(32, 8, 4), 256, 0, stream>>>(
            hid_g, 1024, 4194304,
            w2t + (size_t)g * 4 * 1048576, 1024, 1048576,
            b2 + (size_t)g * 4 * 1024, 1024, am,
            (void*)logit_g, 1024, 4194304, 1024);
        softmax_pv<<<dim3(64, 16), 256, 0, stream>>>(logit_g, vt, attn_b, g);
    }

    // ---- out = attn @ Wo.T + bo -> fp32 (4096 x 1024)
    gemm_bf16_nt<1, 0, 0><<<dim3(32, 8, 1), 256, 0, stream>>>(
        attn_b, 1024, 0, Wo_b, 1024, 0, bo, 0, nullptr,
        d_out, 1024, 0, 1024);
}

// Round 6
// 528.894 us; speedup vs baseline: 4.4848x; 1.0658x over previous
//
#include <hip/hip_runtime.h>

typedef unsigned short u16;
typedef short bf16x8 __attribute__((ext_vector_type(8)));
typedef float f32x4 __attribute__((ext_vector_type(4)));

#define BSZ 4
#define DD 1024
#define LLL 1024

__device__ __forceinline__ float bf2f(u16 u) {
    union { unsigned int i; float f; } w;
    w.i = ((unsigned int)u) << 16;
    return w.f;
}
__device__ __forceinline__ u16 f2bf(float f) {
    union { float fl; unsigned int i; } w;
    w.fl = f;
    w.i += 0x7fffu + ((w.i >> 16) & 1u);   // RNE
    return (u16)(w.i >> 16);
}

// async global->LDS, 16B per lane; LDS dst must be wave-uniform base + lane*16
__device__ __forceinline__ void load_lds16(const u16* g, u16* l) {
    __builtin_amdgcn_global_load_lds(
        (const __attribute__((address_space(1))) unsigned int*)g,
        (__attribute__((address_space(3))) unsigned int*)l, 16, 0, 0);
}

// ---- fused fp32->bf16 converts for x (4096 blk), Wi (2048), Wo (1024)
__global__ void cvt_all(const float* __restrict__ x, const float* __restrict__ Wi,
                        const float* __restrict__ Wo, u16* __restrict__ xb,
                        u16* __restrict__ wib, u16* __restrict__ wob) {
    int b = blockIdx.x;
    const float* in; u16* out;
    if (b < 4096)      { in = x;  out = xb; }
    else if (b < 6144) { in = Wi; out = wib; b -= 4096; }
    else               { in = Wo; out = wob; b -= 6144; }
    const size_t i = ((size_t)b * 256 + threadIdx.x) * 4;
    const float4 v = *(const float4*)(in + i);
    ushort4 o;
    o.x = f2bf(v.x); o.y = f2bf(v.y); o.z = f2bf(v.z); o.w = f2bf(v.w);
    *(ushort4*)(out + i) = o;
}

// ---- batched transpose+convert: in[z][R][C] f32 -> out[z][C][R] bf16
__global__ void transpose_cvt(const float* __restrict__ in, u16* __restrict__ out,
                              int R, int C) {
    __shared__ float tile[32][33];
    const size_t base = (size_t)blockIdx.z * R * C;
    const int c0 = blockIdx.x << 5, r0 = blockIdx.y << 5;
    const int tx = threadIdx.x & 31, ty = threadIdx.x >> 5;   // 256 thr = 32x8
    #pragma unroll
    for (int i = 0; i < 32; i += 8)
        tile[ty + i][tx] = in[base + (size_t)(r0 + ty + i) * C + c0 + tx];
    __syncthreads();
    #pragma unroll
    for (int i = 0; i < 32; i += 8)
        out[base + (size_t)(c0 + ty + i) * R + r0 + tx] = f2bf(tile[tx][ty + i]);
}

// ---- build vt[j][d][m] (j = b*16+k) from proj's v-half
__global__ void build_vt(const u16* __restrict__ proj, u16* __restrict__ vt) {
    __shared__ u16 tile[64][66];
    const int t = threadIdx.x;
    const int m0 = blockIdx.x << 6;
    const int jj = blockIdx.y;
    const int b = jj >> 4, k = jj & 15;
    const int tx = t & 63, ty = t >> 6;
    #pragma unroll
    for (int mi = ty; mi < 64; mi += 4)
        tile[mi][tx] = proj[(size_t)((m0 + mi) * BSZ + b) * 2048 + 1024 + k * 64 + tx];
    __syncthreads();
    #pragma unroll
    for (int di = ty; di < 64; di += 4)
        vt[((size_t)jj * 64 + di) * 1024 + m0 + tx] = tile[tx][di];
}

// ---- generic batched bf16 NT-GEMM: C[r][n] = sum_k A[r][k]*B[n][k] + bias[n]
// 128x128 tile, BK=64, 4 waves, 16x16x32 MFMA, fp32 acc.
// global_load_lds width=16 staging with XOR chunk swizzle (pos = chunk^(row&7)):
// keeps lane-contiguous LDS dst AND spreads ds_read_b128 start banks.
template<int OUT_F32, int RELU, int MASKADD>
__global__ __launch_bounds__(256, 2) void gemm_bf16_nt(
    const u16* __restrict__ A, int lda, long long sA,
    const u16* __restrict__ B, int ldb, long long sB,
    const float* __restrict__ bias, int sBias,
    const float* __restrict__ mask,
    void* __restrict__ C, int ldc, long long sC,
    int K)
{
    __shared__ u16 As[128 * 64];
    __shared__ u16 Bs[128 * 64];
    const int t = threadIdx.x;
    const int z = blockIdx.z;
    const u16* Ab = A + (size_t)z * sA + (size_t)blockIdx.x * 128 * lda;
    const u16* Bb = B + (size_t)z * sB + (size_t)blockIdx.y * 128 * ldb;
    const int wave = t >> 6, lane = t & 63;
    const int wrow = (wave >> 1) << 6;   // 0 / 64
    const int wcol = (wave & 1) << 6;    // 0 / 64
    const int lr = lane & 15, lq = lane >> 4;

    // staging: thread t covers (row = j*32 + t>>3, LDS pos = t&7) for j=0..3;
    // content chunk = pos ^ (row&7)  (XOR swizzle)
    const int srow = t >> 3;                         // 0..31
    const int gchunk = (t & 7) ^ (srow & 7);         // global 8-elem chunk idx
    const u16* ApG = Ab + (size_t)srow * lda + gchunk * 8;
    const u16* BpG = Bb + (size_t)srow * ldb + gchunk * 8;
    u16* AsD = &As[t * 8];
    u16* BsD = &Bs[t * 8];

    // fragment read offsets (chunk c at pos c^(row&7); row&7 == lr&7)
    const int o0 = ((lq     ) ^ (lr & 7)) * 8;       // sub-step s=0
    const int o1 = ((lq + 4) ^ (lr & 7)) * 8;        // sub-step s=1

    f32x4 acc[4][4];
    #pragma unroll
    for (int i = 0; i < 4; i++)
        #pragma unroll
        for (int j = 0; j < 4; j++)
            acc[i][j] = (f32x4){0.f, 0.f, 0.f, 0.f};

    for (int k0 = 0; k0 < K; k0 += 64) {
        __syncthreads();                 // prior reads of As/Bs complete
        #pragma unroll
        for (int j = 0; j < 4; j++) {
            load_lds16(ApG + (size_t)j * 32 * lda + k0, AsD + j * 2048);
            load_lds16(BpG + (size_t)j * 32 * ldb + k0, BsD + j * 2048);
        }
        __syncthreads();                 // compiler drains vmcnt before barrier
        #pragma unroll
        for (int s = 0; s < 2; s++) {
            const int oo = s ? o1 : o0;
            bf16x8 af[4], bfv[4];
            #pragma unroll
            for (int i = 0; i < 4; i++)
                af[i] = *(const bf16x8*)&As[(wrow + i * 16 + lr) * 64 + oo];
            #pragma unroll
            for (int j = 0; j < 4; j++)
                bfv[j] = *(const bf16x8*)&Bs[(wcol + j * 16 + lr) * 64 + oo];
            #pragma unroll
            for (int i = 0; i < 4; i++)
                #pragma unroll
                for (int j = 0; j < 4; j++)
                    acc[i][j] = __builtin_amdgcn_mfma_f32_16x16x32_bf16(
                        af[i], bfv[j], acc[i][j], 0, 0, 0);
        }
    }

    // epilogue: C/D layout col=lane&15, row=quad*4+reg
    const float* biasb = bias + (size_t)z * sBias;
    const size_t row0 = (size_t)blockIdx.x * 128 + wrow + lq * 4;
    const int col0 = blockIdx.y * 128 + wcol + lr;
    #pragma unroll
    for (int j = 0; j < 4; j++) {
        const int col = col0 + j * 16;
        const float bb = biasb[col];
        #pragma unroll
        for (int i = 0; i < 4; i++) {
            #pragma unroll
            for (int r = 0; r < 4; r++) {
                const size_t row = row0 + i * 16 + r;
                float v = acc[i][j][r] + bb;
                if (MASKADD) v += mask[(row >> 2) * (size_t)1024 + col];
                if (RELU) v = fmaxf(v, 0.f);
                const size_t idx = row * (size_t)ldc + col;
                if (OUT_F32) ((float*)C)[(size_t)z * sC + idx] = v;
                else         ((u16*)C)[(size_t)z * sC + idx] = f2bf(v);
            }
        }
    }
}

// ---- softmax (logits pre-masked+biased) + MFMA P@V per (16-row l-tile, p_local)
// group of 4 heads: pl in [0,16), kql = pl>>2, bq = pl&3
__global__ __launch_bounds__(256, 4) void softmax_pv(
    const u16* __restrict__ logits,   // (4, 4096, 1024) bf16, masked
    const u16* __restrict__ vt,       // (64, 64, 1024) bf16: [j=b*16+k][d][m]
    u16* __restrict__ attn,           // (4096, 1024) bf16
    int g)
{
    __shared__ u16 ps[16 * 1032];
    __shared__ float wredm[4][16];
    __shared__ float wreds[4][16];
    const int t = threadIdx.x;
    const int l0 = blockIdx.x << 4;
    const int pl = blockIdx.y;            // 0..15
    const int kql = pl >> 2, bq = pl & 3;
    const int kq = 4 * g + kql;
    const int p = kq * 4 + bq;
    const int bv = p >> 4, kv = p & 15;
    const int jv = bv * 16 + kv;
    const int lane = t & 63, wave = t >> 6;

    float acc[16][4];
    #pragma unroll
    for (int r = 0; r < 16; r++) {
        const ushort4 lv = *(const ushort4*)(logits + (size_t)kql * 4194304
                           + (size_t)((l0 + r) * BSZ + bq) * 1024 + (t << 2));
        acc[r][0] = bf2f(lv.x);
        acc[r][1] = bf2f(lv.y);
        acc[r][2] = bf2f(lv.z);
        acc[r][3] = bf2f(lv.w);
    }

    float rowmax[16];
    #pragma unroll
    for (int r = 0; r < 16; r++) {
        float mx = fmaxf(fmaxf(acc[r][0], acc[r][1]), fmaxf(acc[r][2], acc[r][3]));
        #pragma unroll
        for (int o = 32; o > 0; o >>= 1) mx = fmaxf(mx, __shfl_xor(mx, o));
        if (lane == 0) wredm[wave][r] = mx;
    }
    __syncthreads();
    #pragma unroll
    for (int r = 0; r < 16; r++)
        rowmax[r] = fmaxf(fmaxf(wredm[0][r], wredm[1][r]),
                          fmaxf(wredm[2][r], wredm[3][r]));
    #pragma unroll
    for (int r = 0; r < 16; r++) {
        float s = 0.f;
        #pragma unroll
        for (int jj = 0; jj < 4; jj++) {
            acc[r][jj] = __expf(acc[r][jj] - rowmax[r]);
            s += acc[r][jj];
        }
        #pragma unroll
        for (int o = 32; o > 0; o >>= 1) s += __shfl_xor(s, o);
        if (lane == 0) wreds[wave][r] = s;
    }
    #pragma unroll
    for (int r = 0; r < 16; r++) {
        ushort4 pv;
        pv.x = f2bf(acc[r][0]); pv.y = f2bf(acc[r][1]);
        pv.z = f2bf(acc[r][2]); pv.w = f2bf(acc[r][3]);
        *(ushort4*)&ps[r * 1032 + (t << 2)] = pv;
    }
    __syncthreads();

    // P@V via MFMA: wave handles d in [wave*16, wave*16+16).
    // 4 independent accumulator chains to break the MFMA latency chain.
    const int lr = lane & 15, lq = lane >> 4;
    f32x4 p0 = (f32x4){0.f, 0.f, 0.f, 0.f};
    f32x4 p1 = p0, p2 = p0, p3 = p0;
    const u16* vb = vt + ((size_t)jv * 64 + wave * 16 + lr) * 1024 + lq * 8;
    const u16* pb = &ps[lr * 1032 + lq * 8];
    #pragma unroll
    for (int k0 = 0; k0 < 1024; k0 += 128) {
        p0 = __builtin_amdgcn_mfma_f32_16x16x32_bf16(
            *(const bf16x8*)(pb + k0),      *(const bf16x8*)(vb + k0),      p0, 0, 0, 0);
        p1 = __builtin_amdgcn_mfma_f32_16x16x32_bf16(
            *(const bf16x8*)(pb + k0 + 32), *(const bf16x8*)(vb + k0 + 32), p1, 0, 0, 0);
        p2 = __builtin_amdgcn_mfma_f32_16x16x32_bf16(
            *(const bf16x8*)(pb + k0 + 64), *(const bf16x8*)(vb + k0 + 64), p2, 0, 0, 0);
        p3 = __builtin_amdgcn_mfma_f32_16x16x32_bf16(
            *(const bf16x8*)(pb + k0 + 96), *(const bf16x8*)(vb + k0 + 96), p3, 0, 0, 0);
    }
    const f32x4 po = (p0 + p1) + (p2 + p3);
    #pragma unroll
    for (int ri = 0; ri < 4; ri++) {
        const int row = lq * 4 + ri;
        const float s = wreds[0][row] + wreds[1][row] + wreds[2][row] + wreds[3][row];
        attn[(size_t)((l0 + row) * BSZ + bv) * DD + kv * 64 + wave * 16 + lr] =
            f2bf(po[ri] / s);
    }
}

extern "C" void kernel_launch(void* const* d_in, const int* in_sizes, int n_in,
                              void* d_out, int out_size, void* d_ws, size_t ws_size,
                              hipStream_t stream)
{
    (void)in_sizes; (void)n_in; (void)out_size; (void)ws_size;
    const float* x  = (const float*)d_in[0];
    const float* am = (const float*)d_in[1];
    const float* Wi = (const float*)d_in[2];
    const float* bi = (const float*)d_in[3];
    const float* w1 = (const float*)d_in[4];
    const float* b1 = (const float*)d_in[5];
    const float* w2 = (const float*)d_in[6];
    const float* b2 = (const float*)d_in[7];
    const float* Wo = (const float*)d_in[8];
    const float* bo = (const float*)d_in[9];

    // ws layout (elems, bf16): 68M elems = 136 MB (ws_size = 256 MiB)
    u16* x_b    = (u16*)d_ws;                  // 4096x1024      = 4M
    u16* Wi_b   = x_b    + (size_t)4194304;    // 2048x1024      = 2M
    u16* w1t    = Wi_b   + (size_t)2097152;    // 16 x 1024x64   = 1M
    u16* w2t    = w1t    + (size_t)1048576;    // 16 x 1024x1024 = 16M
    u16* Wo_b   = w2t    + (size_t)16777216;   // 1024x1024      = 1M
    u16* proj_b = Wo_b   + (size_t)1048576;    // 4096x2048      = 8M
    u16* attn_b = proj_b + (size_t)8388608;    // 4096x1024      = 4M
    u16* hid_g  = attn_b + (size_t)4194304;    // 4 x 4096x1024  = 16M
    u16* logit_g= hid_g  + (size_t)16777216;   // 4 x 4096x1024  = 16M
    u16* vt     = x_b;   // alias: x_b dead after proj GEMM

    // ---- prep
    cvt_all<<<7168, 256, 0, stream>>>(x, Wi, Wo, x_b, Wi_b, Wo_b);
    transpose_cvt<<<dim3(32,  2, 16), 256, 0, stream>>>(w1, w1t, 64,   1024);
    transpose_cvt<<<dim3(32, 32, 16), 256, 0, stream>>>(w2, w2t, 1024, 1024);

    // ---- proj = x @ Wi.T + bi  -> bf16 (4096 x 2048)
    gemm_bf16_nt<0, 0, 0><<<dim3(32, 16, 1), 256, 0, stream>>>(
        x_b, 1024, 0, Wi_b, 1024, 0, bi, 0, nullptr,
        (void*)proj_b, 2048, 0, 1024);

    // ---- vt[j][d][m] from proj's v-half (overwrites x_b)
    build_vt<<<dim3(16, 64), 256, 0, stream>>>(proj_b, vt);

    // ---- per head-group (4 heads): hid -> logits(+mask) -> softmax+PV
    for (int g = 0; g < 4; g++) {
        gemm_bf16_nt<0, 1, 0><<<dim3(32, 8, 4), 256, 0, stream>>>(
            proj_b + (size_t)g * 256, 2048, 64,
            w1t + (size_t)g * 4 * 65536, 64, 65536,
            b1 + (size_t)g * 4 * 1024, 1024, nullptr,
            (void*)hid_g, 1024, 4194304, 64);
        gemm_bf16_nt<0, 0, 1><<<dim3(32, 8, 4), 256, 0, stream>>>(
            hid_g, 1024, 4194304,
            w2t + (size_t)g * 4 * 1048576, 1024, 1048576,
            b2 + (size_t)g * 4 * 1024, 1024, am,
            (void*)logit_g, 1024, 4194304, 1024);
        softmax_pv<<<dim3(64, 16), 256, 0, stream>>>(logit_g, vt, attn_b, g);
    }

    // ---- out = attn @ Wo.T + bo -> fp32 (4096 x 1024)
    gemm_bf16_nt<1, 0, 0><<<dim3(32, 8, 1), 256, 0, stream>>>(
        attn_b, 1024, 0, Wo_b, 1024, 0, bo, 0, nullptr,
        d_out, 1024, 0, 1024);
}

// Round 7
// 420.302 us; speedup vs baseline: 5.6436x; 1.2584x over previous
//
#include <hip/hip_runtime.h>

typedef unsigned short u16;
typedef short bf16x8 __attribute__((ext_vector_type(8)));
typedef float f32x4 __attribute__((ext_vector_type(4)));

#define BSZ 4
#define DD 1024
#define LLL 1024

__device__ __forceinline__ float bf2f(u16 u) {
    union { unsigned int i; float f; } w;
    w.i = ((unsigned int)u) << 16;
    return w.f;
}
__device__ __forceinline__ u16 f2bf(float f) {
    union { float fl; unsigned int i; } w;
    w.fl = f;
    w.i += 0x7fffu + ((w.i >> 16) & 1u);   // RNE
    return (u16)(w.i >> 16);
}

// async global->LDS, 16B per lane; LDS dst must be wave-uniform base + lane*16
__device__ __forceinline__ void load_lds16(const u16* g, u16* l) {
    __builtin_amdgcn_global_load_lds(
        (const __attribute__((address_space(1))) unsigned int*)g,
        (__attribute__((address_space(3))) unsigned int*)l, 16, 0, 0);
}

// ---- fused fp32->bf16 converts for x (4096 blk), Wi (2048), Wo (1024)
__global__ void cvt_all(const float* __restrict__ x, const float* __restrict__ Wi,
                        const float* __restrict__ Wo, u16* __restrict__ xb,
                        u16* __restrict__ wib, u16* __restrict__ wob) {
    int b = blockIdx.x;
    const float* in; u16* out;
    if (b < 4096)      { in = x;  out = xb; }
    else if (b < 6144) { in = Wi; out = wib; b -= 4096; }
    else               { in = Wo; out = wob; b -= 6144; }
    const size_t i = ((size_t)b * 256 + threadIdx.x) * 4;
    const float4 v = *(const float4*)(in + i);
    ushort4 o;
    o.x = f2bf(v.x); o.y = f2bf(v.y); o.z = f2bf(v.z); o.w = f2bf(v.w);
    *(ushort4*)(out + i) = o;
}

// ---- batched transpose+convert: in[z][R][C] f32 -> out[z][C][R] bf16
__global__ void transpose_cvt(const float* __restrict__ in, u16* __restrict__ out,
                              int R, int C) {
    __shared__ float tile[32][33];
    const size_t base = (size_t)blockIdx.z * R * C;
    const int c0 = blockIdx.x << 5, r0 = blockIdx.y << 5;
    const int tx = threadIdx.x & 31, ty = threadIdx.x >> 5;   // 256 thr = 32x8
    #pragma unroll
    for (int i = 0; i < 32; i += 8)
        tile[ty + i][tx] = in[base + (size_t)(r0 + ty + i) * C + c0 + tx];
    __syncthreads();
    #pragma unroll
    for (int i = 0; i < 32; i += 8)
        out[base + (size_t)(c0 + ty + i) * R + r0 + tx] = f2bf(tile[tx][ty + i]);
}

// ---- build vt[j][d][m], d-dim padded to 80: d=64 is the ones-column (rowsum
// trick), d=65..79 zero. j = b*16+k.
__global__ void build_vt(const u16* __restrict__ proj, u16* __restrict__ vt) {
    __shared__ u16 tile[64][66];
    const int t = threadIdx.x;
    const int m0 = blockIdx.x << 6;
    const int jj = blockIdx.y;
    const int b = jj >> 4, k = jj & 15;
    const int tx = t & 63, ty = t >> 6;
    #pragma unroll
    for (int mi = ty; mi < 64; mi += 4)
        tile[mi][tx] = proj[(size_t)((m0 + mi) * BSZ + b) * 2048 + 1024 + k * 64 + tx];
    __syncthreads();
    #pragma unroll
    for (int di = ty; di < 64; di += 4)
        vt[((size_t)jj * 80 + di) * 1024 + m0 + tx] = tile[tx][di];
    #pragma unroll
    for (int di = 64 + ty; di < 80; di += 4)
        vt[((size_t)jj * 80 + di) * 1024 + m0 + tx] = (di == 64) ? 0x3F80 : 0;
}

// ---- generic batched bf16 NT-GEMM (round-6-proven): 128x128 tile, BK=64,
// XOR chunk swizzle, global_load_lds width=16.
template<int OUT_F32, int RELU>
__global__ __launch_bounds__(256, 2) void gemm_bf16_nt(
    const u16* __restrict__ A, int lda, long long sA,
    const u16* __restrict__ B, int ldb, long long sB,
    const float* __restrict__ bias, int sBias,
    void* __restrict__ C, int ldc, long long sC,
    int K)
{
    __shared__ u16 As[128 * 64];
    __shared__ u16 Bs[128 * 64];
    const int t = threadIdx.x;
    const int z = blockIdx.z;
    const u16* Ab = A + (size_t)z * sA + (size_t)blockIdx.x * 128 * lda;
    const u16* Bb = B + (size_t)z * sB + (size_t)blockIdx.y * 128 * ldb;
    const int wave = t >> 6, lane = t & 63;
    const int wrow = (wave >> 1) << 6;
    const int wcol = (wave & 1) << 6;
    const int lr = lane & 15, lq = lane >> 4;
    const int srow = t >> 3;
    const int gchunk = (t & 7) ^ (srow & 7);
    const u16* ApG = Ab + (size_t)srow * lda + gchunk * 8;
    const u16* BpG = Bb + (size_t)srow * ldb + gchunk * 8;
    u16* AsD = &As[t * 8];
    u16* BsD = &Bs[t * 8];
    const int o0 = ((lq    ) ^ (lr & 7)) * 8;
    const int o1 = ((lq + 4) ^ (lr & 7)) * 8;

    f32x4 acc[4][4];
    #pragma unroll
    for (int i = 0; i < 4; i++)
        #pragma unroll
        for (int j = 0; j < 4; j++)
            acc[i][j] = (f32x4){0.f, 0.f, 0.f, 0.f};

    for (int k0 = 0; k0 < K; k0 += 64) {
        __syncthreads();
        #pragma unroll
        for (int j = 0; j < 4; j++) {
            load_lds16(ApG + (size_t)j * 32 * lda + k0, AsD + j * 2048);
            load_lds16(BpG + (size_t)j * 32 * ldb + k0, BsD + j * 2048);
        }
        __syncthreads();
        #pragma unroll
        for (int s = 0; s < 2; s++) {
            const int oo = s ? o1 : o0;
            bf16x8 af[4], bfv[4];
            #pragma unroll
            for (int i = 0; i < 4; i++)
                af[i] = *(const bf16x8*)&As[(wrow + i * 16 + lr) * 64 + oo];
            #pragma unroll
            for (int j = 0; j < 4; j++)
                bfv[j] = *(const bf16x8*)&Bs[(wcol + j * 16 + lr) * 64 + oo];
            #pragma unroll
            for (int i = 0; i < 4; i++)
                #pragma unroll
                for (int j = 0; j < 4; j++)
                    acc[i][j] = __builtin_amdgcn_mfma_f32_16x16x32_bf16(
                        af[i], bfv[j], acc[i][j], 0, 0, 0);
        }
    }

    const float* biasb = bias + (size_t)z * sBias;
    const size_t row0 = (size_t)blockIdx.x * 128 + wrow + lq * 4;
    const int col0 = blockIdx.y * 128 + wcol + lr;
    #pragma unroll
    for (int j = 0; j < 4; j++) {
        const int col = col0 + j * 16;
        const float bb = biasb[col];
        #pragma unroll
        for (int i = 0; i < 4; i++) {
            #pragma unroll
            for (int r = 0; r < 4; r++) {
                const size_t row = row0 + i * 16 + r;
                float v = acc[i][j][r] + bb;
                if (RELU) v = fmaxf(v, 0.f);
                const size_t idx = row * (size_t)ldc + col;
                if (OUT_F32) ((float*)C)[(size_t)z * sC + idx] = v;
                else         ((u16*)C)[(size_t)z * sC + idx] = f2bf(v);
            }
        }
    }
}

// ---- fused logits+softmax+PV. Block = (strip pair, p). Per part: 64 l-rows,
// causal m-tiles only (pairing s with 15-s gives exactly 9 tiles/block).
// Fixed-max softmax (shift-invariant; logits are O(1), masked -> exp=0).
// Rowsum comes from vt's ones-column (d=64).
__global__ __launch_bounds__(256, 2) void fused_attn(
    const u16* __restrict__ hid,    // (16, 4096, 1024) bf16
    const u16* __restrict__ w2t,    // (16, 1024, 1024) bf16 [k][m][h]
    const float* __restrict__ b2,   // (16, 1024) fp32
    const float* __restrict__ mask, // (1024, 1024) fp32
    const u16* __restrict__ vt,     // (64, 80, 1024) bf16
    u16* __restrict__ attn)         // (4096, 1024) bf16
{
    __shared__ u16 As[64 * 64];     // hid tile: 64 rows x 64 k
    __shared__ u16 Bs[128 * 64];    // w2t tile: 128 m x 64 k
    __shared__ u16 Ps[64 * 136];    // probs tile: 64 rows x 128 m (+8 pad)
    const int t = threadIdx.x;
    const int pair = blockIdx.x;    // 0..7
    const int p = blockIdx.y;       // 0..63
    const int kq = p >> 2, bq = p & 3;
    const int bv = p >> 4, kv = p & 15;
    const int jv = bv * 16 + kv;
    const int wave = t >> 6, lane = t & 63;
    const int lr = lane & 15, lq = lane >> 4;
    const int wi = wave >> 1, wj = wave & 1;
    const int srow = t >> 3;                    // 0..31
    const int gch = (t & 7) ^ (srow & 7);       // XOR chunk swizzle
    const int o0 = ((lq    ) ^ (lr & 7)) * 8;
    const int o1 = ((lq + 4) ^ (lr & 7)) * 8;
    const u16* hb = hid + (size_t)kq * 4194304;
    const u16* wb = w2t + (size_t)kq * 1048576 + (size_t)srow * 1024 + gch * 8;

    for (int part = 0; part < 2; part++) {
        const int s = part ? (15 - pair) : pair;
        const int l0 = s * 64;
        const int nt = ((s * 64 + 63) >> 7) + 1;   // causal m-tile count
        f32x4 o[5];
        #pragma unroll
        for (int j = 0; j < 5; j++) o[j] = (f32x4){0.f, 0.f, 0.f, 0.f};
        const u16* ApG = hb + ((size_t)((l0 + srow) * BSZ + bq)) * 1024 + gch * 8;

        for (int mt = 0; mt < nt; mt++) {
            // ---- logits tile 64x128, K=1024
            f32x4 acc[2][4];
            #pragma unroll
            for (int i = 0; i < 2; i++)
                #pragma unroll
                for (int j = 0; j < 4; j++)
                    acc[i][j] = (f32x4){0.f, 0.f, 0.f, 0.f};
            for (int k0 = 0; k0 < 1024; k0 += 64) {
                __syncthreads();
                load_lds16(ApG + k0, &As[t * 8]);
                load_lds16(ApG + (size_t)32 * BSZ * 1024 + k0, &As[2048 + t * 8]);
                #pragma unroll
                for (int j2 = 0; j2 < 4; j2++)
                    load_lds16(wb + (size_t)(mt * 128 + j2 * 32) * 1024 + k0,
                               &Bs[j2 * 2048 + t * 8]);
                __syncthreads();
                #pragma unroll
                for (int s2 = 0; s2 < 2; s2++) {
                    const int oo = s2 ? o1 : o0;
                    bf16x8 af[2], bfv[4];
                    #pragma unroll
                    for (int i = 0; i < 2; i++)
                        af[i] = *(const bf16x8*)&As[(wi * 32 + i * 16 + lr) * 64 + oo];
                    #pragma unroll
                    for (int j = 0; j < 4; j++)
                        bfv[j] = *(const bf16x8*)&Bs[(wj * 64 + j * 16 + lr) * 64 + oo];
                    #pragma unroll
                    for (int i = 0; i < 2; i++)
                        #pragma unroll
                        for (int j = 0; j < 4; j++)
                            acc[i][j] = __builtin_amdgcn_mfma_f32_16x16x32_bf16(
                                af[i], bfv[j], acc[i][j], 0, 0, 0);
                }
            }
            // ---- +b2 +mask, exp (fixed max 0) -> Ps (bf16)
            __syncthreads();       // prior PV reads of Ps complete
            float b2v[4];
            #pragma unroll
            for (int j = 0; j < 4; j++)
                b2v[j] = b2[kq * 1024 + mt * 128 + wj * 64 + j * 16 + lr];
            #pragma unroll
            for (int i = 0; i < 2; i++) {
                #pragma unroll
                for (int j = 0; j < 4; j++) {
                    const int cp = wj * 64 + j * 16 + lr;
                    #pragma unroll
                    for (int r = 0; r < 4; r++) {
                        const int rp = wi * 32 + i * 16 + lq * 4 + r;
                        const float mv =
                            mask[(size_t)(l0 + rp) * 1024 + mt * 128 + cp];
                        Ps[rp * 136 + cp] = f2bf(__expf(acc[i][j][r] + b2v[j] + mv));
                    }
                }
            }
            __syncthreads();
            // ---- O += P @ V^T : wave owns rows [wave*16, wave*16+16), 80 d-cols
            const u16* vbb = vt + (size_t)jv * 80 * 1024 + mt * 128 + lq * 8;
            #pragma unroll
            for (int kc = 0; kc < 4; kc++) {
                const bf16x8 a =
                    *(const bf16x8*)&Ps[(wave * 16 + lr) * 136 + kc * 32 + lq * 8];
                #pragma unroll
                for (int j = 0; j < 5; j++) {
                    const bf16x8 b =
                        *(const bf16x8*)(vbb + (size_t)(j * 16 + lr) * 1024 + kc * 32);
                    o[j] = __builtin_amdgcn_mfma_f32_16x16x32_bf16(a, b, o[j], 0, 0, 0);
                }
            }
        }
        // ---- normalize by rowsum (ones-column, d=64 -> o[4], col lane lr==0)
        float sden[4];
        #pragma unroll
        for (int ri = 0; ri < 4; ri++)
            sden[ri] = __shfl(o[4][ri], lq << 4);
        #pragma unroll
        for (int j = 0; j < 4; j++) {
            #pragma unroll
            for (int ri = 0; ri < 4; ri++) {
                const int gl = l0 + wave * 16 + lq * 4 + ri;
                attn[(size_t)(gl * BSZ + bv) * 1024 + kv * 64 + j * 16 + lr] =
                    f2bf(o[j][ri] / sden[ri]);
            }
        }
    }
}

extern "C" void kernel_launch(void* const* d_in, const int* in_sizes, int n_in,
                              void* d_out, int out_size, void* d_ws, size_t ws_size,
                              hipStream_t stream)
{
    (void)in_sizes; (void)n_in; (void)out_size; (void)ws_size;
    const float* x  = (const float*)d_in[0];
    const float* am = (const float*)d_in[1];
    const float* Wi = (const float*)d_in[2];
    const float* bi = (const float*)d_in[3];
    const float* w1 = (const float*)d_in[4];
    const float* b1 = (const float*)d_in[5];
    const float* w2 = (const float*)d_in[6];
    const float* b2 = (const float*)d_in[7];
    const float* Wo = (const float*)d_in[8];
    const float* bo = (const float*)d_in[9];

    // ws layout (bf16 elems): 110.06M elems = 220 MB <= 256 MiB
    u16* x_b    = (u16*)d_ws;                  // 4096x1024       = 4M
    u16* Wi_b   = x_b    + (size_t)4194304;    // 2048x1024       = 2M
    u16* w1t    = Wi_b   + (size_t)2097152;    // 16 x 1024x64    = 1M
    u16* w2t    = w1t    + (size_t)1048576;    // 16 x 1024x1024  = 16M
    u16* Wo_b   = w2t    + (size_t)16777216;   // 1024x1024       = 1M
    u16* proj_b = Wo_b   + (size_t)1048576;    // 4096x2048       = 8M
    u16* attn_b = proj_b + (size_t)8388608;    // 4096x1024       = 4M
    u16* vt     = attn_b + (size_t)4194304;    // 64 x 80 x 1024  = 5M
    u16* hid_a  = vt     + (size_t)5242880;    // 16 x 4096x1024  = 64M

    // ---- prep
    cvt_all<<<7168, 256, 0, stream>>>(x, Wi, Wo, x_b, Wi_b, Wo_b);
    transpose_cvt<<<dim3(32,  2, 16), 256, 0, stream>>>(w1, w1t, 64,   1024);
    transpose_cvt<<<dim3(32, 32, 16), 256, 0, stream>>>(w2, w2t, 1024, 1024);

    // ---- proj = x @ Wi.T + bi  -> bf16 (4096 x 2048)
    gemm_bf16_nt<0, 0><<<dim3(32, 16, 1), 256, 0, stream>>>(
        x_b, 1024, 0, Wi_b, 1024, 0, bi, 0, (void*)proj_b, 2048, 0, 1024);

    // ---- vt[j][d(80)][m] from proj's v-half (with ones-column at d=64)
    build_vt<<<dim3(16, 64), 256, 0, stream>>>(proj_b, vt);

    // ---- hid = relu(q @ w1t.T + b1) for all 16 heads (z=16)
    gemm_bf16_nt<0, 1><<<dim3(32, 8, 16), 256, 0, stream>>>(
        proj_b, 2048, 64,
        w1t, 64, 65536,
        b1, 1024,
        (void*)hid_a, 1024, 4194304, 64);

    // ---- fused logits + softmax + PV (causal-skip, balanced strip pairs)
    fused_attn<<<dim3(8, 64), 256, 0, stream>>>(hid_a, w2t, b2, am, vt, attn_b);

    // ---- out = attn @ Wo.T + bo -> fp32 (4096 x 1024)
    gemm_bf16_nt<1, 0><<<dim3(32, 8, 1), 256, 0, stream>>>(
        attn_b, 1024, 0, Wo_b, 1024, 0, bo, 0, d_out, 1024, 0, 1024);
}